// Round 1
// baseline (747.529 us; speedup 1.0000x reference)
//
#include <hip/hip_runtime.h>

#define NPIX 110592            // 48^3
#define NTILES 1728            // NPIX / 64, per batch
#define K1_BLOCKS 864          // grid for K1 (each does 4 tiles, b-aligned)
#define K1_TPB 4
#define PART_STRIDE 4224       // 4*32*32 ctx + 128 rowsum

// ws layout (float offsets)
#define WS_WT    0                       // 64*384 transposed w_qkv
#define WS_CTX   24576                   // 2*4*32*32
#define WS_RS    32768                   // 2*128
#define WS_AT    33024                   // 2*128*64  (A transposed: [hc][o])
#define WS_PART  49408                   // partials

// ---------------- K0: transpose w_qkv (384x64 -> 64x384) -----------------
__global__ void k0_wt(const float* __restrict__ w, float* __restrict__ wT) {
    int idx = blockIdx.x * 256 + threadIdx.x;
    if (idx < 384 * 64) {
        int r = idx >> 6, c = idx & 63;
        wT[c * 384 + r] = w[idx];
    }
}

// ---------------- K1: k,v GEMM + ctx/rowsum accumulation -----------------
// block = 256 thr (4 waves). wave og handles kv rows og*64..+64 in phase1,
// head h=og in phase2. lane p = pixel within 64-wide tile.
__global__ __launch_bounds__(256, 2)
void k1_ctx(const float* __restrict__ x, const float* __restrict__ wT,
            float* __restrict__ part, int usePart, int R) {
    __shared__ float kv[256 * 64];       // XOR-swizzled, exactly 64 KB
    const int blk = blockIdx.x;
    const int p  = threadIdx.x & 63;
    const int og = __builtin_amdgcn_readfirstlane(threadIdx.x >> 6);
    const int b  = blk / (K1_BLOCKS / 2);
    const int h  = og;
    const int c0 = (p >> 3) << 2;
    const int d0 = (p & 7) << 2;

    float cc[16];
    #pragma unroll
    for (int i = 0; i < 16; ++i) cc[i] = 0.f;
    float rs[4] = {0.f, 0.f, 0.f, 0.f};

    for (int tt = 0; tt < K1_TPB; ++tt) {
        const int  flat = blk * K1_TPB + tt;       // b*NTILES + tile
        const int  tile = flat - b * NTILES;
        const long i0   = (long)tile * 64;
        const float* xg = x + (long)b * 64 * NPIX + i0 + p;
        float xr[64];
        #pragma unroll
        for (int c = 0; c < 64; ++c) xr[c] = xg[(long)c * NPIX];

        if (tt) __syncthreads();                   // prev phase2 done before overwrite

        // phase 1: kv rows og*64..+64 (qkv rows 128+o_local), 4 chunks of 16
        const bool isK = og < 2;
        for (int chunk = 0; chunk < 4; ++chunk) {
            const int o0 = og * 64 + chunk * 16;
            float acc[16];
            #pragma unroll
            for (int j = 0; j < 16; ++j) acc[j] = 0.f;
            #pragma unroll 4
            for (int c = 0; c < 64; ++c) {
                const float* wr = wT + c * 384 + 128 + o0;   // wave-uniform -> s_load
                const float xv = xr[c];
                #pragma unroll
                for (int j = 0; j < 16; ++j) acc[j] = fmaf(wr[j], xv, acc[j]);
            }
            #pragma unroll
            for (int j = 0; j < 16; ++j) {
                const int o = o0 + j;
                const float v = isK ? __expf(acc[j]) : acc[j];
                kv[o * 64 + (p ^ (o & 63))] = v;
            }
        }
        __syncthreads();

        // phase 2: ctx[c0..+4][d0..+4] += ek * v over 64 pixels
        for (int q = 0; q < 64; ++q) {
            float ek[4], vv[4];
            #pragma unroll
            for (int a = 0; a < 4; ++a) {
                const int o = h * 32 + c0 + a;
                ek[a] = kv[o * 64 + (q ^ (o & 63))];
            }
            #pragma unroll
            for (int a = 0; a < 4; ++a) {
                const int o = 128 + h * 32 + d0 + a;
                vv[a] = kv[o * 64 + (q ^ (o & 63))];
            }
            #pragma unroll
            for (int a = 0; a < 4; ++a)
                #pragma unroll
                for (int e = 0; e < 4; ++e)
                    cc[a * 4 + e] = fmaf(ek[a], vv[e], cc[a * 4 + e]);
            if (d0 == 0) {
                #pragma unroll
                for (int a = 0; a < 4; ++a) rs[a] += ek[a];
            }
        }
    }

    // epilogue: write per-block partial, or atomic into replicas
    if (usePart) {
        float* pp = part + (long)blk * PART_STRIDE;
        #pragma unroll
        for (int a = 0; a < 4; ++a)
            #pragma unroll
            for (int e = 0; e < 4; ++e)
                pp[h * 1024 + (c0 + a) * 32 + d0 + e] = cc[a * 4 + e];
        if (d0 == 0) {
            #pragma unroll
            for (int a = 0; a < 4; ++a) pp[4096 + h * 32 + c0 + a] = rs[a];
        }
    } else {
        float* pp = part + (long)(b * R + (blk % R)) * PART_STRIDE;
        #pragma unroll
        for (int a = 0; a < 4; ++a)
            #pragma unroll
            for (int e = 0; e < 4; ++e)
                atomicAdd(&pp[h * 1024 + (c0 + a) * 32 + d0 + e], cc[a * 4 + e]);
        if (d0 == 0) {
            #pragma unroll
            for (int a = 0; a < 4; ++a) atomicAdd(&pp[4096 + h * 32 + c0 + a], rs[a]);
        }
    }
}

// ---------------- K1b: reduce partials -> ctxU, rsum ---------------------
__global__ void k1b_reduce(float* __restrict__ ws, int PB) {
    int idx = blockIdx.x * 256 + threadIdx.x;        // [0, 2*4224)
    if (idx >= 2 * PART_STRIDE) return;
    const int b = idx / PART_STRIDE;
    const int e = idx % PART_STRIDE;
    const float* part = ws + WS_PART;
    const int half = PB >> 1;
    float s = 0.f;
    for (int pi = b * half; pi < b * half + half; ++pi)
        s += part[(long)pi * PART_STRIDE + e];
    if (e < 4096) ws[WS_CTX + b * 4096 + e] = s;
    else          ws[WS_RS + b * 128 + (e - 4096)] = s;
}

// ---------------- K2: A_T[hc][o] = sum_d w_out[o,hd]*ctx[h][c][d]/rsum ---
__global__ __launch_bounds__(256)
void k2_prepA(const float* __restrict__ wout, float* __restrict__ ws) {
    __shared__ float wo[64 * 129];       // padded: conflict-free strided reads
    __shared__ float ct[4096];
    __shared__ float rsum[128];
    const int b  = blockIdx.x >> 3;
    const int jb = blockIdx.x & 7;
    const int tid = threadIdx.x;
    for (int i = tid; i < 8192; i += 256) wo[(i >> 7) * 129 + (i & 127)] = wout[i];
    for (int i = tid; i < 4096; i += 256) ct[i] = ws[WS_CTX + b * 4096 + i];
    if (tid < 128) rsum[tid] = ws[WS_RS + b * 128 + tid];
    __syncthreads();
    float* AT = ws + WS_AT + b * 8192;
    for (int j = jb * 4; j < jb * 4 + 4; ++j) {
        const int m  = j * 256 + tid;
        const int hc = m >> 6;
        const int o  = m & 63;
        const int hh = hc >> 5, c = hc & 31;
        float s = 0.f;
        #pragma unroll
        for (int d = 0; d < 32; ++d)
            s = fmaf(wo[o * 129 + hh * 32 + d], ct[hh * 1024 + c * 32 + d], s);
        AT[hc * 64 + o] = s / rsum[hc];
    }
}

// ---------------- K3: q GEMM + per-pixel softmax + A@q + bias ------------
__global__ __launch_bounds__(256, 2)
void k3_out(const float* __restrict__ x, const float* __restrict__ wT,
            const float* __restrict__ bout, const float* __restrict__ ws,
            float* __restrict__ out) {
    __shared__ float ql[128 * 64];
    const int  blk  = blockIdx.x;
    const int  b    = blk / NTILES;
    const int  tile = blk % NTILES;
    const long i0   = (long)tile * 64;
    const int  p  = threadIdx.x & 63;
    const int  og = __builtin_amdgcn_readfirstlane(threadIdx.x >> 6);
    const float* xg = x + (long)b * 64 * NPIX + i0 + p;
    float xr[64];
    #pragma unroll
    for (int c = 0; c < 64; ++c) xr[c] = xg[(long)c * NPIX];

    // phase 1: q rows og*32..+32 (qkv rows 0..127)
    for (int chunk = 0; chunk < 2; ++chunk) {
        const int o0 = og * 32 + chunk * 16;
        float acc[16];
        #pragma unroll
        for (int j = 0; j < 16; ++j) acc[j] = 0.f;
        #pragma unroll 4
        for (int c = 0; c < 64; ++c) {
            const float* wr = wT + c * 384 + o0;           // wave-uniform -> s_load
            const float xv = xr[c];
            #pragma unroll
            for (int j = 0; j < 16; ++j) acc[j] = fmaf(wr[j], xv, acc[j]);
        }
        #pragma unroll
        for (int j = 0; j < 16; ++j) ql[(o0 + j) * 64 + p] = acc[j];
    }
    __syncthreads();

    // phase 2: softmax over the 32 dims of head h=og, column p
    {
        const int hh = og;
        float qv[32];
        #pragma unroll
        for (int c = 0; c < 32; ++c) qv[c] = ql[(hh * 32 + c) * 64 + p];
        float m = qv[0];
        #pragma unroll
        for (int c = 1; c < 32; ++c) m = fmaxf(m, qv[c]);
        float s = 0.f;
        #pragma unroll
        for (int c = 0; c < 32; ++c) { qv[c] = __expf(qv[c] - m); s += qv[c]; }
        const float inv = 1.0f / s;
        #pragma unroll
        for (int c = 0; c < 32; ++c) ql[(hh * 32 + c) * 64 + p] = qv[c] * inv;
    }
    __syncthreads();

    // phase 3: out[o0..+16][p] = b_out + sum_hc A_T[hc][o] * qsm[hc][p]
    {
        const int o0 = og * 16;
        const float* AT = ws + WS_AT + b * 8192;
        float acc[16];
        #pragma unroll
        for (int j = 0; j < 16; ++j) acc[j] = bout[o0 + j];
        for (int hc = 0; hc < 128; ++hc) {
            const float qv = ql[hc * 64 + p];
            const float* ar = AT + hc * 64 + o0;           // wave-uniform -> s_load
            #pragma unroll
            for (int j = 0; j < 16; ++j) acc[j] = fmaf(ar[j], qv, acc[j]);
        }
        float* op = out + ((long)b * 64 + o0) * NPIX + i0 + p;
        #pragma unroll
        for (int j = 0; j < 16; ++j) op[(long)j * NPIX] = acc[j];
    }
}

extern "C" void kernel_launch(void* const* d_in, const int* in_sizes, int n_in,
                              void* d_out, int out_size, void* d_ws, size_t ws_size,
                              hipStream_t stream) {
    (void)in_sizes; (void)n_in; (void)out_size;
    const float* x     = (const float*)d_in[0];
    const float* w_qkv = (const float*)d_in[1];
    const float* w_out = (const float*)d_in[2];
    const float* b_out = (const float*)d_in[3];
    float* out = (float*)d_out;
    float* ws  = (float*)d_ws;

    const size_t need_part = ((size_t)WS_PART + (size_t)K1_BLOCKS * PART_STRIDE) * 4;
    const int usePart = (ws_size >= need_part) ? 1 : 0;
    int R = 8;
    const size_t need_r8 = ((size_t)WS_PART + (size_t)2 * 8 * PART_STRIDE) * 4;
    if (!usePart && ws_size < need_r8) R = 1;
    const int PB = usePart ? K1_BLOCKS : 2 * R;
    float* part = ws + WS_PART;

    hipLaunchKernelGGL(k0_wt, dim3(96), dim3(256), 0, stream, w_qkv, ws + WS_WT);
    if (!usePart)
        hipMemsetAsync(part, 0, (size_t)PB * PART_STRIDE * 4, stream);
    hipLaunchKernelGGL(k1_ctx, dim3(K1_BLOCKS), dim3(256), 0, stream,
                       x, ws + WS_WT, part, usePart, R);
    hipLaunchKernelGGL(k1b_reduce, dim3(33), dim3(256), 0, stream, ws, PB);
    hipLaunchKernelGGL(k2_prepA, dim3(16), dim3(256), 0, stream, w_out, ws);
    hipLaunchKernelGGL(k3_out, dim3(2 * NTILES), dim3(256), 0, stream,
                       x, ws + WS_WT, b_out, ws, out);
}

// Round 2
// 448.490 us; speedup vs baseline: 1.6668x; 1.6668x over previous
//
#include <hip/hip_runtime.h>

#define NPIX 110592            // 48^3
#define NTILES 1728            // NPIX / 64, per batch
#define K1_BLOCKS 1728         // grid for K1 (each does 2 tiles, b-aligned)
#define K1_TPB 2
#define PART_STRIDE 4224       // 4*32*32 ctx + 128 rowsum

// ws layout (float offsets)
#define WS_WT    0                       // 64*384 transposed w_qkv
#define WS_CTX   24576                   // 2*4*32*32
#define WS_RS    32768                   // 2*128
#define WS_AT    33024                   // 2*128*64  (A transposed: [hc][o])
#define WS_PART  49408                   // partials

// swizzled LDS addressing for k1: kv[pix][col], col XOR'd per row so that
// per-lane b128 writes (all lanes same col range) spread across bank-quads.
#define SWZ(row, col) ((row) * 256 + ((col) ^ (((row) & 7) << 2)))

// ---------------- K0: transpose w_qkv (384x64 -> 64x384) -----------------
__global__ void k0_wt(const float* __restrict__ w, float* __restrict__ wT) {
    int idx = blockIdx.x * 256 + threadIdx.x;
    if (idx < 384 * 64) {
        int r = idx >> 6, c = idx & 63;
        wT[c * 384 + r] = w[idx];
    }
}

// ---------------- K1: k,v GEMM + ctx/rowsum accumulation -----------------
// block = 256 thr (4 waves). wave og computes qkv rows 128+og*64..+64 in
// phase1 (k heads 0..3 for og<2, v heads for og>=2); phase2: wave og owns
// head h=og. lane p = pixel within 64-wide tile.
__global__ __launch_bounds__(256, 2)
void k1_ctx(const float* __restrict__ x, const float* __restrict__ wT,
            float* __restrict__ part, int usePart, int R) {
    __shared__ float kv[64 * 256];       // [pix][col], swizzled; 64 KB
    const int blk = blockIdx.x;
    const int p  = threadIdx.x & 63;
    const int og = __builtin_amdgcn_readfirstlane(threadIdx.x >> 6);
    const int b  = blk / (K1_BLOCKS / 2);
    const int h  = og;
    const int c0 = (p >> 3) << 2;
    const int d0 = (p & 7) << 2;

    float cc[16];
    #pragma unroll
    for (int i = 0; i < 16; ++i) cc[i] = 0.f;
    float rs[4] = {0.f, 0.f, 0.f, 0.f};

    #pragma unroll 1
    for (int tt = 0; tt < K1_TPB; ++tt) {
        const int  flat = blk * K1_TPB + tt;       // b*NTILES + tile
        const int  tile = flat - b * NTILES;
        const long i0   = (long)tile * 64;
        const float* xg = x + (long)b * 64 * NPIX + i0 + p;
        float xr[64];
        #pragma unroll
        for (int c = 0; c < 64; ++c) xr[c] = xg[(long)c * NPIX];

        if (tt) __syncthreads();                   // prev phase2 done before overwrite

        // phase 1: qkv rows 128 + og*64 .. +64, 4 chunks of 16
        const bool isK = og < 2;
        #pragma unroll 1
        for (int chunk = 0; chunk < 4; ++chunk) {
            const int o0 = og * 64 + chunk * 16;
            float acc[16];
            #pragma unroll
            for (int j = 0; j < 16; ++j) acc[j] = 0.f;
            #pragma unroll
            for (int c = 0; c < 64; ++c) {
                const float* wr = wT + c * 384 + 128 + o0;   // wave-uniform -> s_load
                const float xv = xr[c];
                #pragma unroll
                for (int j = 0; j < 16; ++j) acc[j] = fmaf(wr[j], xv, acc[j]);
            }
            #pragma unroll
            for (int j = 0; j < 16; ++j)
                if (isK) acc[j] = __expf(acc[j]);
            #pragma unroll
            for (int k2 = 0; k2 < 4; ++k2) {
                float4 st = make_float4(acc[4*k2], acc[4*k2+1], acc[4*k2+2], acc[4*k2+3]);
                *(float4*)&kv[SWZ(p, o0 + 4 * k2)] = st;
            }
        }
        __syncthreads();

        // phase 2: ctx[c0..+4][d0..+4] += ek * v over 64 pixels, b128 reads
        #pragma unroll 4
        for (int q = 0; q < 64; ++q) {
            const float4 ekv = *(const float4*)&kv[SWZ(q, h * 32 + c0)];
            const float4 vvv = *(const float4*)&kv[SWZ(q, 128 + h * 32 + d0)];
            const float ek[4] = {ekv.x, ekv.y, ekv.z, ekv.w};
            const float vv[4] = {vvv.x, vvv.y, vvv.z, vvv.w};
            #pragma unroll
            for (int a = 0; a < 4; ++a)
                #pragma unroll
                for (int e = 0; e < 4; ++e)
                    cc[a * 4 + e] = fmaf(ek[a], vv[e], cc[a * 4 + e]);
            // every d0-group computes the identical rowsum; only d0==0 writes
            #pragma unroll
            for (int a = 0; a < 4; ++a) rs[a] += ek[a];
        }
    }

    // epilogue: write per-block partial, or atomic into replicas
    if (usePart) {
        float* pp = part + (long)blk * PART_STRIDE;
        #pragma unroll
        for (int a = 0; a < 4; ++a)
            #pragma unroll
            for (int e = 0; e < 4; ++e)
                pp[h * 1024 + (c0 + a) * 32 + d0 + e] = cc[a * 4 + e];
        if (d0 == 0) {
            #pragma unroll
            for (int a = 0; a < 4; ++a) pp[4096 + h * 32 + c0 + a] = rs[a];
        }
    } else {
        float* pp = part + (long)(b * R + (blk % R)) * PART_STRIDE;
        #pragma unroll
        for (int a = 0; a < 4; ++a)
            #pragma unroll
            for (int e = 0; e < 4; ++e)
                atomicAdd(&pp[h * 1024 + (c0 + a) * 32 + d0 + e], cc[a * 4 + e]);
        if (d0 == 0) {
            #pragma unroll
            for (int a = 0; a < 4; ++a) atomicAdd(&pp[4096 + h * 32 + c0 + a], rs[a]);
        }
    }
}

// ---------------- K1b: reduce partials -> ctxU, rsum (atomic, sliced) ----
// grid = 8 slices * 2 b * 33 chunks = 528 blocks, 128 thr.
__global__ __launch_bounds__(128)
void k1b_reduce(float* __restrict__ ws, int PB) {
    const int S = 8;
    const int chunk = blockIdx.x % 33;
    const int rem   = blockIdx.x / 33;
    const int b     = rem & 1;
    const int slice = rem >> 1;
    const int j = chunk * 128 + threadIdx.x;       // [0, 4224)
    const int PBh = PB >> 1;
    const int range = PBh / S;
    const float* part = ws + WS_PART;
    float s = 0.f;
    const long base = ((long)b * PBh + (long)slice * range) * PART_STRIDE + j;
    for (int i = 0; i < range; ++i) s += part[base + (long)i * PART_STRIDE];
    float* dst = (j < 4096) ? (ws + WS_CTX + b * 4096 + j)
                            : (ws + WS_RS + b * 128 + (j - 4096));
    atomicAdd(dst, s);
}

// ---------------- K2: A_T[hc][o] = sum_d w_out[o,hd]*ctx[h][c][d]/rsum ---
__global__ __launch_bounds__(256)
void k2_prepA(const float* __restrict__ wout, float* __restrict__ ws) {
    __shared__ float wo[64 * 129];       // padded: conflict-free strided reads
    __shared__ float ct[4096];
    __shared__ float rsum[128];
    const int b  = blockIdx.x >> 3;
    const int jb = blockIdx.x & 7;
    const int tid = threadIdx.x;
    for (int i = tid; i < 8192; i += 256) wo[(i >> 7) * 129 + (i & 127)] = wout[i];
    for (int i = tid; i < 4096; i += 256) ct[i] = ws[WS_CTX + b * 4096 + i];
    if (tid < 128) rsum[tid] = ws[WS_RS + b * 128 + tid];
    __syncthreads();
    float* AT = ws + WS_AT + b * 8192;
    for (int j = jb * 4; j < jb * 4 + 4; ++j) {
        const int m  = j * 256 + tid;
        const int hc = m >> 6;
        const int o  = m & 63;
        const int hh = hc >> 5, c = hc & 31;
        float s = 0.f;
        #pragma unroll
        for (int d = 0; d < 32; ++d)
            s = fmaf(wo[o * 129 + hh * 32 + d], ct[hh * 1024 + c * 32 + d], s);
        AT[hc * 64 + o] = s / rsum[hc];
    }
}

// ---------------- K3: q GEMM + per-pixel softmax + A@q + bias ------------
__global__ __launch_bounds__(256, 2)
void k3_out(const float* __restrict__ x, const float* __restrict__ wT,
            const float* __restrict__ bout, const float* __restrict__ ws,
            float* __restrict__ out) {
    __shared__ float ql[128 * 64];
    const int  blk  = blockIdx.x;
    const int  b    = blk / NTILES;
    const int  tile = blk % NTILES;
    const long i0   = (long)tile * 64;
    const int  p  = threadIdx.x & 63;
    const int  og = __builtin_amdgcn_readfirstlane(threadIdx.x >> 6);
    const float* xg = x + (long)b * 64 * NPIX + i0 + p;
    float xr[64];
    #pragma unroll
    for (int c = 0; c < 64; ++c) xr[c] = xg[(long)c * NPIX];

    // phase 1: q rows og*32..+32 (qkv rows 0..127)
    #pragma unroll 1
    for (int chunk = 0; chunk < 2; ++chunk) {
        const int o0 = og * 32 + chunk * 16;
        float acc[16];
        #pragma unroll
        for (int j = 0; j < 16; ++j) acc[j] = 0.f;
        #pragma unroll
        for (int c = 0; c < 64; ++c) {
            const float* wr = wT + c * 384 + o0;           // wave-uniform -> s_load
            const float xv = xr[c];
            #pragma unroll
            for (int j = 0; j < 16; ++j) acc[j] = fmaf(wr[j], xv, acc[j]);
        }
        #pragma unroll
        for (int j = 0; j < 16; ++j) ql[(o0 + j) * 64 + p] = acc[j];
    }
    // no barrier needed: phase 2 reads only this wave's own rows

    // phase 2: softmax over the 32 dims of head h=og, column p
    {
        const int hh = og;
        float qv[32];
        #pragma unroll
        for (int c = 0; c < 32; ++c) qv[c] = ql[(hh * 32 + c) * 64 + p];
        float m = qv[0];
        #pragma unroll
        for (int c = 1; c < 32; ++c) m = fmaxf(m, qv[c]);
        float s = 0.f;
        #pragma unroll
        for (int c = 0; c < 32; ++c) { qv[c] = __expf(qv[c] - m); s += qv[c]; }
        const float inv = 1.0f / s;
        #pragma unroll
        for (int c = 0; c < 32; ++c) ql[(hh * 32 + c) * 64 + p] = qv[c] * inv;
    }
    __syncthreads();

    // phase 3: out[o0..+16][p] = b_out + sum_hc A_T[hc][o] * qsm[hc][p]
    {
        const int o0 = og * 16;
        const float* AT = ws + WS_AT + b * 8192;
        float acc[16];
        #pragma unroll
        for (int j = 0; j < 16; ++j) acc[j] = bout[o0 + j];
        #pragma unroll 2
        for (int hc = 0; hc < 128; ++hc) {
            const float qv = ql[hc * 64 + p];
            const float* ar = AT + hc * 64 + o0;           // wave-uniform -> s_load
            #pragma unroll
            for (int j = 0; j < 16; ++j) acc[j] = fmaf(ar[j], qv, acc[j]);
        }
        float* op = out + ((long)b * 64 + o0) * NPIX + i0 + p;
        #pragma unroll
        for (int j = 0; j < 16; ++j) op[(long)j * NPIX] = acc[j];
    }
}

extern "C" void kernel_launch(void* const* d_in, const int* in_sizes, int n_in,
                              void* d_out, int out_size, void* d_ws, size_t ws_size,
                              hipStream_t stream) {
    (void)in_sizes; (void)n_in; (void)out_size;
    const float* x     = (const float*)d_in[0];
    const float* w_qkv = (const float*)d_in[1];
    const float* w_out = (const float*)d_in[2];
    const float* b_out = (const float*)d_in[3];
    float* out = (float*)d_out;
    float* ws  = (float*)d_ws;

    const size_t need_part = ((size_t)WS_PART + (size_t)K1_BLOCKS * PART_STRIDE) * 4;
    const int usePart = (ws_size >= need_part) ? 1 : 0;
    int R = 8;
    const size_t need_r8 = ((size_t)WS_PART + (size_t)2 * 8 * PART_STRIDE) * 4;
    if (!usePart && ws_size < need_r8) R = 1;
    const int PB = usePart ? K1_BLOCKS : 2 * R;
    float* part = ws + WS_PART;

    hipLaunchKernelGGL(k0_wt, dim3(96), dim3(256), 0, stream, w_qkv, ws + WS_WT);
    if (!usePart)
        hipMemsetAsync(part, 0, (size_t)PB * PART_STRIDE * 4, stream);
    hipLaunchKernelGGL(k1_ctx, dim3(K1_BLOCKS), dim3(256), 0, stream,
                       x, ws + WS_WT, part, usePart, R);
    hipMemsetAsync(ws + WS_CTX, 0, (size_t)(2 * PART_STRIDE) * 4, stream);
    hipLaunchKernelGGL(k1b_reduce, dim3(528), dim3(128), 0, stream, ws, PB);
    hipLaunchKernelGGL(k2_prepA, dim3(16), dim3(256), 0, stream, w_out, ws);
    hipLaunchKernelGGL(k3_out, dim3(2 * NTILES), dim3(256), 0, stream,
                       x, ws + WS_WT, b_out, ws, out);
}

// Round 3
// 442.194 us; speedup vs baseline: 1.6905x; 1.0142x over previous
//
#include <hip/hip_runtime.h>

typedef unsigned int u32;

#define NPIX 110592            // 48^3
#define NTILES 1728            // NPIX / 64, per batch
#define K1_BLOCKS 1728         // grid for K1 (each does 2 tiles, b-aligned)
#define K1_TPB 2
#define PART_STRIDE 4224       // 4*32*32 ctx + 128 rowsum

// ws layout (float offsets)
#define WS_WT    0                       // 64*384 transposed w_qkv
#define WS_CTX   24576                   // 2*4*32*32
#define WS_RS    32768                   // 2*128
#define WS_AT    33024                   // 2*128*64  (A transposed: [hc][o])
#define WS_PART  49408                   // partials

// kv LDS (bf16): [pix][256 cols], 16B-granule XOR swizzle (col in bf16 units):
// swizzled col = col ^ ((row & 7) << 3). Bijective, keeps 8-bf16 granules.
#define KCOL(row, col) ((col) ^ (((row) & 7) << 3))

__device__ __forceinline__ void gll16(const float* g, float* l) {
    typedef const __attribute__((address_space(1))) unsigned int* gp_t;
    typedef __attribute__((address_space(3))) unsigned int* lp_t;
    __builtin_amdgcn_global_load_lds((gp_t)g, (lp_t)l, 16, 0, 0);
}
__device__ __forceinline__ u32 f2bf(float f) {           // RNE f32->bf16
    u32 u = __float_as_uint(f);
    return (u + 0x7FFFu + ((u >> 16) & 1u)) >> 16;
}
__device__ __forceinline__ float bfl(u32 u) { return __uint_as_float(u << 16); }
__device__ __forceinline__ float bfh(u32 u) { return __uint_as_float(u & 0xFFFF0000u); }

// ---------------- K0: transpose w_qkv (384x64 -> 64x384) -----------------
__global__ void k0_wt(const float* __restrict__ w, float* __restrict__ wT) {
    int idx = blockIdx.x * 256 + threadIdx.x;
    if (idx < 384 * 64) {
        int r = idx >> 6, c = idx & 63;
        wT[c * 384 + r] = w[idx];
    }
}

// ---------------- K1: k,v GEMM + ctx/rowsum accumulation -----------------
// 256 thr / 4 waves. Wave og: stages 16 x-rows, computes qkv rows
// 128+og*64..+64 (phase1), owns head h=og (phase2). lane p = pixel in tile.
__global__ __launch_bounds__(256, 3)
void k1_ctx(const float* __restrict__ x, const float* __restrict__ wT,
            float* __restrict__ part, int usePart, int R) {
    __shared__ float xt[64 * 64];        // [c][p] f32, 16 KB
    __shared__ u32   kv[64 * 128];       // [pix][256 bf16], swizzled, 32 KB
    const int blk = blockIdx.x;
    const int p   = threadIdx.x & 63;
    const int og  = __builtin_amdgcn_readfirstlane(threadIdx.x >> 6);
    const int b   = blk / (K1_BLOCKS / 2);
    const int h   = og;
    const int c0  = (p >> 3) << 2;
    const int d0  = (p & 7) << 2;
    const float* xb = x + (long)b * 64 * NPIX;
    // staging: wave og covers rows og*16..+16; instr i: 4 rows, lane l ->
    // row += l>>4, col = (l&15)*4
    const int srow = (p >> 4);
    const int scol = (p & 15) << 2;

    float cc[16];
    #pragma unroll
    for (int i = 0; i < 16; ++i) cc[i] = 0.f;
    float rs[4] = {0.f, 0.f, 0.f, 0.f};

    {   // prologue: stage tile 0
        const long i0 = (long)(blk * K1_TPB - b * NTILES) * 64;
        #pragma unroll
        for (int i = 0; i < 4; ++i) {
            const int r0 = og * 16 + i * 4;
            gll16(xb + (long)(r0 + srow) * NPIX + i0 + scol, &xt[r0 * 64]);
        }
    }

    #pragma unroll 1
    for (int tt = 0; tt < K1_TPB; ++tt) {
        asm volatile("s_waitcnt vmcnt(0)" ::: "memory");
        __syncthreads();                           // x[tt] staged by all waves
        float xr[64];
        #pragma unroll
        for (int c = 0; c < 64; ++c) xr[c] = xt[c * 64 + p];
        __syncthreads();                           // all waves read x
        if (tt + 1 < K1_TPB) {                     // prefetch next tile's x
            const long i0 = (long)(blk * K1_TPB + tt + 1 - b * NTILES) * 64;
            #pragma unroll
            for (int i = 0; i < 4; ++i) {
                const int r0 = og * 16 + i * 4;
                gll16(xb + (long)(r0 + srow) * NPIX + i0 + scol, &xt[r0 * 64]);
            }
        }

        // phase 1: qkv rows 128 + og*64 .. +64, 4 chunks of 16
        const bool isK = og < 2;
        #pragma unroll 1
        for (int chunk = 0; chunk < 4; ++chunk) {
            const int o0 = og * 64 + chunk * 16;
            float acc[16];
            #pragma unroll
            for (int j = 0; j < 16; ++j) acc[j] = 0.f;
            #pragma unroll
            for (int c = 0; c < 64; ++c) {
                const float* wr = wT + c * 384 + 128 + o0;   // uniform -> s_load
                const float xv = xr[c];
                #pragma unroll
                for (int j = 0; j < 16; ++j) acc[j] = fmaf(wr[j], xv, acc[j]);
            }
            #pragma unroll
            for (int j = 0; j < 16; ++j)
                if (isK) acc[j] = __expf(acc[j]);
            u32 pk[8];
            #pragma unroll
            for (int j = 0; j < 8; ++j)
                pk[j] = f2bf(acc[2 * j]) | (f2bf(acc[2 * j + 1]) << 16);
            const int g0 = (p * 256 + KCOL(p, o0)) >> 1;       // u32 idx, 16B-al
            const int g1 = (p * 256 + KCOL(p, o0 + 8)) >> 1;
            *(uint4*)&kv[g0] = make_uint4(pk[0], pk[1], pk[2], pk[3]);
            *(uint4*)&kv[g1] = make_uint4(pk[4], pk[5], pk[6], pk[7]);
        }
        __syncthreads();                           // kv ready

        // phase 2: ctx[c0..+4][d0..+4] += ek * v over 64 pixels
        #pragma unroll 4
        for (int q = 0; q < 64; ++q) {
            const uint2 eu = *(const uint2*)&kv[(q * 256 + KCOL(q, h * 32 + c0)) >> 1];
            const uint2 vu = *(const uint2*)&kv[(q * 256 + KCOL(q, 128 + h * 32 + d0)) >> 1];
            const float ek[4] = { bfl(eu.x), bfh(eu.x), bfl(eu.y), bfh(eu.y) };
            const float vv[4] = { bfl(vu.x), bfh(vu.x), bfl(vu.y), bfh(vu.y) };
            #pragma unroll
            for (int a = 0; a < 4; ++a)
                #pragma unroll
                for (int e = 0; e < 4; ++e)
                    cc[a * 4 + e] = fmaf(ek[a], vv[e], cc[a * 4 + e]);
            #pragma unroll
            for (int a = 0; a < 4; ++a) rs[a] += ek[a];
        }
    }

    // epilogue: write per-block partial, or atomic into replicas
    if (usePart) {
        float* pp = part + (long)blk * PART_STRIDE;
        #pragma unroll
        for (int a = 0; a < 4; ++a)
            #pragma unroll
            for (int e = 0; e < 4; ++e)
                pp[h * 1024 + (c0 + a) * 32 + d0 + e] = cc[a * 4 + e];
        if (d0 == 0) {
            #pragma unroll
            for (int a = 0; a < 4; ++a) pp[4096 + h * 32 + c0 + a] = rs[a];
        }
    } else {
        float* pp = part + (long)(b * R + (blk % R)) * PART_STRIDE;
        #pragma unroll
        for (int a = 0; a < 4; ++a)
            #pragma unroll
            for (int e = 0; e < 4; ++e)
                atomicAdd(&pp[h * 1024 + (c0 + a) * 32 + d0 + e], cc[a * 4 + e]);
        if (d0 == 0) {
            #pragma unroll
            for (int a = 0; a < 4; ++a) atomicAdd(&pp[4096 + h * 32 + c0 + a], rs[a]);
        }
    }
}

// ---------------- K1b: reduce partials -> ctxU, rsum (atomic, sliced) ----
__global__ __launch_bounds__(128)
void k1b_reduce(float* __restrict__ ws, int PB) {
    const int S = 8;
    const int chunk = blockIdx.x % 33;
    const int rem   = blockIdx.x / 33;
    const int b     = rem & 1;
    const int slice = rem >> 1;
    const int j = chunk * 128 + threadIdx.x;       // [0, 4224)
    const int PBh = PB >> 1;
    const int range = PBh / S;
    const float* part = ws + WS_PART;
    float s = 0.f;
    const long base = ((long)b * PBh + (long)slice * range) * PART_STRIDE + j;
    for (int i = 0; i < range; ++i) s += part[base + (long)i * PART_STRIDE];
    float* dst = (j < 4096) ? (ws + WS_CTX + b * 4096 + j)
                            : (ws + WS_RS + b * 128 + (j - 4096));
    atomicAdd(dst, s);
}

// ---------------- K2: A_T[hc][o] = sum_d w_out[o,hd]*ctx[h][c][d]/rsum ---
__global__ __launch_bounds__(256)
void k2_prepA(const float* __restrict__ wout, float* __restrict__ ws) {
    __shared__ float wo[64 * 129];
    __shared__ float ct[4096];
    __shared__ float rsum[128];
    const int b  = blockIdx.x >> 3;
    const int jb = blockIdx.x & 7;
    const int tid = threadIdx.x;
    for (int i = tid; i < 8192; i += 256) wo[(i >> 7) * 129 + (i & 127)] = wout[i];
    for (int i = tid; i < 4096; i += 256) ct[i] = ws[WS_CTX + b * 4096 + i];
    if (tid < 128) rsum[tid] = ws[WS_RS + b * 128 + tid];
    __syncthreads();
    float* AT = ws + WS_AT + b * 8192;
    for (int j = jb * 4; j < jb * 4 + 4; ++j) {
        const int m  = j * 256 + tid;
        const int hc = m >> 6;
        const int o  = m & 63;
        const int hh = hc >> 5, c = hc & 31;
        float s = 0.f;
        #pragma unroll
        for (int d = 0; d < 32; ++d)
            s = fmaf(wo[o * 129 + hh * 32 + d], ct[hh * 1024 + c * 32 + d], s);
        AT[hc * 64 + o] = s / rsum[hc];
    }
}

// ---------------- K3: q GEMM + per-pixel softmax + A@q + bias ------------
__global__ __launch_bounds__(256, 3)
void k3_out(const float* __restrict__ x, const float* __restrict__ wT,
            const float* __restrict__ bout, const float* __restrict__ ws,
            float* __restrict__ out) {
    __shared__ float xt[64 * 64];        // staged x tile, 16 KB
    __shared__ float ql[128 * 64];       // q / softmax(q), 32 KB
    const int  blk  = blockIdx.x;
    const int  b    = blk / NTILES;
    const int  tile = blk % NTILES;
    const long i0   = (long)tile * 64;
    const int  p  = threadIdx.x & 63;
    const int  og = __builtin_amdgcn_readfirstlane(threadIdx.x >> 6);
    const float* xb = x + (long)b * 64 * NPIX;
    const int srow = (p >> 4);
    const int scol = (p & 15) << 2;

    #pragma unroll
    for (int i = 0; i < 4; ++i) {
        const int r0 = og * 16 + i * 4;
        gll16(xb + (long)(r0 + srow) * NPIX + i0 + scol, &xt[r0 * 64]);
    }
    asm volatile("s_waitcnt vmcnt(0)" ::: "memory");
    __syncthreads();
    float xr[64];
    #pragma unroll
    for (int c = 0; c < 64; ++c) xr[c] = xt[c * 64 + p];

    // phase 1: q rows og*32..+32 (qkv rows 0..127)
    #pragma unroll 1
    for (int chunk = 0; chunk < 2; ++chunk) {
        const int o0 = og * 32 + chunk * 16;
        float acc[16];
        #pragma unroll
        for (int j = 0; j < 16; ++j) acc[j] = 0.f;
        #pragma unroll
        for (int c = 0; c < 64; ++c) {
            const float* wr = wT + c * 384 + o0;           // uniform -> s_load
            const float xv = xr[c];
            #pragma unroll
            for (int j = 0; j < 16; ++j) acc[j] = fmaf(wr[j], xv, acc[j]);
        }
        #pragma unroll
        for (int j = 0; j < 16; ++j) ql[(o0 + j) * 64 + p] = acc[j];
    }
    // no barrier: phase 2 reads only this wave's own rows

    // phase 2: softmax over the 32 dims of head h=og, column p
    {
        const int hh = og;
        float qv[32];
        #pragma unroll
        for (int c = 0; c < 32; ++c) qv[c] = ql[(hh * 32 + c) * 64 + p];
        float m = qv[0];
        #pragma unroll
        for (int c = 1; c < 32; ++c) m = fmaxf(m, qv[c]);
        float s = 0.f;
        #pragma unroll
        for (int c = 0; c < 32; ++c) { qv[c] = __expf(qv[c] - m); s += qv[c]; }
        const float inv = 1.0f / s;
        #pragma unroll
        for (int c = 0; c < 32; ++c) ql[(hh * 32 + c) * 64 + p] = qv[c] * inv;
    }
    __syncthreads();

    // phase 3: out[o0..+16][p] = b_out + sum_hc A_T[hc][o] * qsm[hc][p]
    {
        const int o0 = og * 16;
        const float* AT = ws + WS_AT + b * 8192;
        float acc[16];
        #pragma unroll
        for (int j = 0; j < 16; ++j) acc[j] = bout[o0 + j];
        #pragma unroll 2
        for (int hc = 0; hc < 128; ++hc) {
            const float qv = ql[hc * 64 + p];
            const float* ar = AT + hc * 64 + o0;           // uniform -> s_load
            #pragma unroll
            for (int j = 0; j < 16; ++j) acc[j] = fmaf(ar[j], qv, acc[j]);
        }
        float* op = out + ((long)b * 64 + o0) * NPIX + i0 + p;
        #pragma unroll
        for (int j = 0; j < 16; ++j) op[(long)j * NPIX] = acc[j];
    }
}

extern "C" void kernel_launch(void* const* d_in, const int* in_sizes, int n_in,
                              void* d_out, int out_size, void* d_ws, size_t ws_size,
                              hipStream_t stream) {
    (void)in_sizes; (void)n_in; (void)out_size;
    const float* x     = (const float*)d_in[0];
    const float* w_qkv = (const float*)d_in[1];
    const float* w_out = (const float*)d_in[2];
    const float* b_out = (const float*)d_in[3];
    float* out = (float*)d_out;
    float* ws  = (float*)d_ws;

    const size_t need_part = ((size_t)WS_PART + (size_t)K1_BLOCKS * PART_STRIDE) * 4;
    const int usePart = (ws_size >= need_part) ? 1 : 0;
    int R = 8;
    const size_t need_r8 = ((size_t)WS_PART + (size_t)2 * 8 * PART_STRIDE) * 4;
    if (!usePart && ws_size < need_r8) R = 1;
    const int PB = usePart ? K1_BLOCKS : 2 * R;
    float* part = ws + WS_PART;

    hipLaunchKernelGGL(k0_wt, dim3(96), dim3(256), 0, stream, w_qkv, ws + WS_WT);
    if (!usePart)
        hipMemsetAsync(part, 0, (size_t)PB * PART_STRIDE * 4, stream);
    hipLaunchKernelGGL(k1_ctx, dim3(K1_BLOCKS), dim3(256), 0, stream,
                       x, ws + WS_WT, part, usePart, R);
    hipMemsetAsync(ws + WS_CTX, 0, (size_t)(2 * PART_STRIDE) * 4, stream);
    hipLaunchKernelGGL(k1b_reduce, dim3(528), dim3(128), 0, stream, ws, PB);
    hipLaunchKernelGGL(k2_prepA, dim3(16), dim3(256), 0, stream, w_out, ws);
    hipLaunchKernelGGL(k3_out, dim3(2 * NTILES), dim3(256), 0, stream,
                       x, ws + WS_WT, b_out, ws, out);
}